// Round 11
// baseline (380.632 us; speedup 1.0000x reference)
//
#include <hip/hip_runtime.h>
#include <cmath>

// ConformalModelLogits forward (randomized=True, allow_zero_sets=False).
// One 64-lane wave per row. C=1000 -> 250 float4 chunks; lane l owns chunks
// {l, l+64, l+128, l+192} = 16 classes in registers.
//
// Monotone threshold => prediction set is a sorted prefix; penalties bound its
// length (<=10 here), so a few wave-level pops replace the full 1000-sort.
//
// R4: 180us. R5: u64 keys + top-2 + shfl penalties -> ~119us (chain shortened).
// R8 (issue-count cut): neutral. R10 (launch_bounds + fewer divs): neutral.
// => model: bound by the serial __shfl dependency chain (ds_bpermute ~100cyc).
// R11: PAIR extraction — one 6-step butterfly returns the global top-2
//     remaining (4->2 merge network on u64 keys); ~5 rounds instead of ~10.
//     Winner found by key equality (keys unique): no ballot/shfl-idx.
//     Per-lane top-3 precompute => O(1) refill for a lane's first two pops.

typedef float f32x4 __attribute__((ext_vector_type(4)));
typedef unsigned long long u64;

__global__ __launch_bounds__(256, 4) void conformal_kernel(
    const float* __restrict__ logits,
    const float* __restrict__ penalties,
    const float* __restrict__ u,
    const float* __restrict__ Tptr,
    const float* __restrict__ Qptr,
    float* __restrict__ outL,
    float* __restrict__ outM,
    float* __restrict__ outS,
    int B, int C)
{
    const int lane = threadIdx.x & 63;
    const int row  = blockIdx.x * 4 + (threadIdx.x >> 6);
    if (row >= B) return;

    const float tau = Qptr[0];
    const float Tv  = Tptr[0];
    const int   nch = C >> 2;                  // 250 float4 chunks per row
    const f32x4* xrow4 = reinterpret_cast<const f32x4*>(logits + (size_t)row * C);

    const float pl = penalties[lane < C ? lane : 0];   // pcs increments via shfl
    const float uu = u[row];

    f32x4 xv[4];
    float sc[16];                              // z, then raw e = exp(z - m)
    bool  valid[4];

    // ---- load + z = x/T, row max ----  (bit-exact vs reference)
    float m = -INFINITY;
    #pragma unroll
    for (int s = 0; s < 4; ++s) {
        const int ch = lane + (s << 6);
        valid[s] = (ch < nch);
        if (valid[s]) {
            const f32x4 q = xrow4[ch];
            xv[s] = q;
            const float z0 = q.x / Tv, z1 = q.y / Tv, z2 = q.z / Tv, z3 = q.w / Tv;
            sc[s*4+0] = z0; sc[s*4+1] = z1; sc[s*4+2] = z2; sc[s*4+3] = z3;
            m = fmaxf(m, fmaxf(fmaxf(z0, z1), fmaxf(z2, z3)));
        } else {
            xv[s] = (f32x4){0.f, 0.f, 0.f, 0.f};
            sc[s*4+0] = -INFINITY; sc[s*4+1] = -INFINITY;
            sc[s*4+2] = -INFINITY; sc[s*4+3] = -INFINITY;
        }
    }
    #pragma unroll
    for (int off = 32; off > 0; off >>= 1)
        m = fmaxf(m, __shfl_xor(m, off, 64));

    // ---- exp + sum (raw e kept; winners divided on demand) ----
    float sum = 0.f;
    #pragma unroll
    for (int i = 0; i < 16; ++i) {
        const float e = expf(sc[i] - m);       // -INF tail -> 0
        sc[i] = e;
        sum += e;
    }
    #pragma unroll
    for (int off = 32; off > 0; off >>= 1)
        sum += __shfl_xor(sum, off, 64);

    // ---- u64 keys: (e_bits<<32) | (0xFFFFFFFF - cls); e>=0 so bit order ==
    // value order; ties resolve to smaller class (argsort-stable). ----
    unsigned rem = 0u;
    #pragma unroll
    for (int s = 0; s < 4; ++s)
        if (valid[s]) rem |= (0xFu << (s << 2));
    unsigned memb = 0u;

    // per-lane top-3
    u64 k1 = 0, k2 = 0, k3 = 0;
    #pragma unroll
    for (int i = 0; i < 16; ++i) {
        if (rem & (1u << i)) {
            const int s = i >> 2, j = i & 3;
            const unsigned cls = (unsigned)(((lane + (s << 6)) << 2) + j);
            const u64 kk = ((u64)__float_as_uint(sc[i]) << 32) |
                           (u64)(0xFFFFFFFFu - cls);
            if (kk > k1)      { k3 = k2; k2 = k1; k1 = kk; }
            else if (kk > k2) { k3 = k2; k2 = kk; }
            else if (kk > k3) { k3 = kk; }
        }
    }

    u64 h1 = k1, h2 = k2;                      // lane's next-two candidates
    int nused = 0;

    float cum = 0.f, pen = 0.f;
    int   k = 0;
    int   szb;
    u64   wlast = 0;
    float V = 1.0f;
    bool  done = false;

    while (!done) {
        // ---- one butterfly, global top-2 of all remaining (pair merge) ----
        u64 a1 = h1, a2 = h2;
        #pragma unroll
        for (int off = 32; off > 0; off >>= 1) {
            const u64 b1 = __shfl_xor(a1, off, 64);
            const u64 b2 = __shfl_xor(a2, off, 64);
            const u64 n1 = (a1 > b1) ? a1 : b1;
            const u64 lo = (a1 > b1) ? b1 : a1;
            const u64 m2 = (a2 > b2) ? a2 : b2;
            a1 = n1;
            a2 = (lo > m2) ? lo : m2;
        }
        const u64 w1 = a1, w2 = a2;

        // ---- wave-uniform threshold logic for positions k and k+1 ----
        bool mark2 = false;
        {
            const float val1  = __uint_as_float((unsigned)(w1 >> 32)) / sum;
            const float pk1   = (k < 64) ? __shfl(pl, k, 64) : penalties[k];
            const float penk1 = pen + pk1;
            if (cum + val1 + penk1 <= tau) {
                cum += val1; pen = penk1; ++k;
                if (k >= C) {
                    szb = C; V = (tau - (cum - val1) - penk1) / val1;
                    wlast = w1; done = true;
                } else {
                    const float val2  = __uint_as_float((unsigned)(w2 >> 32)) / sum;
                    const float pk2   = (k < 64) ? __shfl(pl, k, 64) : penalties[k];
                    const float penk2 = pen + pk2;
                    mark2 = true;              // w2 occupies position k
                    if (cum + val2 + penk2 <= tau) {
                        cum += val2; pen = penk2; ++k;
                        if (k >= C) {
                            szb = C; V = (tau - (cum - val2) - penk2) / val2;
                            wlast = w2; done = true;
                        }
                    } else {
                        szb = k + 1; V = (tau - cum - penk2) / val2;
                        wlast = w2; done = true;
                    }
                }
            } else {
                szb = k + 1; V = (tau - cum - penk1) / val1;
                wlast = w1; done = true;
            }
        }

        // ---- owner updates (keys unique; w2 never equals any h-bigger case).
        // h2==w1 impossible (w1 is the global max; h2 < h1 <= w1).
        const bool own1 = (w1 != 0) && (h1 == w1);
        const bool own2 = mark2 && (w2 != 0) && (h1 == w2 || h2 == w2);
        if (own1) {
            const unsigned cls = 0xFFFFFFFFu - (unsigned)(w1 & 0xFFFFFFFFull);
            const int ch = (int)cls >> 2;
            const int slot = ((ch >> 6) << 2) | ((int)cls & 3);
            rem &= ~(1u << slot); memb |= (1u << slot);
        }
        if (own2) {
            const unsigned cls = 0xFFFFFFFFu - (unsigned)(w2 & 0xFFFFFFFFull);
            const int ch = (int)cls >> 2;
            const int slot = ((ch >> 6) << 2) | ((int)cls & 3);
            rem &= ~(1u << slot); memb |= (1u << slot);
        }
        if ((own1 || own2) && !done) {
            nused += (own1 ? 1 : 0) + (own2 ? 1 : 0);
            if (nused == 1) { h1 = k2; h2 = k3; }
            else {
                // rare: lane served >=2 pops -> rescan remaining for top-2
                u64 b1 = 0, b2 = 0;
                #pragma unroll
                for (int i = 0; i < 16; ++i) {
                    if (rem & (1u << i)) {
                        const int s = i >> 2, j = i & 3;
                        const unsigned cls =
                            (unsigned)(((lane + (s << 6)) << 2) + j);
                        const u64 kk = ((u64)__float_as_uint(sc[i]) << 32) |
                                       (u64)(0xFFFFFFFFu - cls);
                        if (kk > b1)      { b2 = b1; b1 = kk; }
                        else if (kk > b2) { b2 = kk; }
                    }
                }
                h1 = b1; h2 = b2;              // 0-sentinels if exhausted
            }
        }
    }

    const int last_idx = (int)(0xFFFFFFFFu - (unsigned)(wlast & 0xFFFFFFFFull));

    // ---- randomized shrink, clamps ----
    int sizes = szb - ((uu >= V) ? 1 : 0);
    const bool full = (tau == 1.0f);
    if (full) sizes = C;
    if (sizes < 1) sizes = 1;
    const bool drop_last = (!full) && (sizes < szb);

    // ---- fused outputs: logits copy, mask, sizes (nontemporal) ----
    f32x4* oL4 = reinterpret_cast<f32x4*>(outL + (size_t)row * C);
    f32x4* oM4 = reinterpret_cast<f32x4*>(outM + (size_t)row * C);
    #pragma unroll
    for (int s = 0; s < 4; ++s) {
        const int ch = lane + (s << 6);
        if (!valid[s]) continue;
        __builtin_nontemporal_store(xv[s], &oL4[ch]);
        f32x4 mk;
        #pragma unroll
        for (int j = 0; j < 4; ++j) {
            const int slot = (s << 2) | j;
            const int cls  = (ch << 2) | j;
            const bool in_set = full ||
                (((memb >> slot) & 1u) && !(drop_last && cls == last_idx));
            mk[j] = in_set ? 1.0f : 0.0f;
        }
        __builtin_nontemporal_store(mk, &oM4[ch]);
    }
    if (lane == 0) outS[row] = (float)sizes;
}

extern "C" void kernel_launch(void* const* d_in, const int* in_sizes, int n_in,
                              void* d_out, int out_size, void* d_ws, size_t ws_size,
                              hipStream_t stream) {
    const float* logits    = (const float*)d_in[0];
    const float* penalties = (const float*)d_in[1];
    const float* u         = (const float*)d_in[2];
    const float* T         = (const float*)d_in[3];
    const float* Qhat      = (const float*)d_in[4];

    const int C = in_sizes[1];   // penalties: (1, C)
    const int B = in_sizes[2];   // u: (B,)

    float* out  = (float*)d_out;
    float* outL = out;                              // [B*C] logits pass-through
    float* outM = out + (size_t)B * C;              // [B*C] set mask as float
    float* outS = out + 2 * (size_t)B * C;          // [B]   sizes as float

    const int blocks = (B + 3) / 4;                 // 4 rows (waves) per block
    conformal_kernel<<<blocks, 256, 0, stream>>>(
        logits, penalties, u, T, Qhat, outL, outM, outS, B, C);
}